// Round 1
// baseline (9563.045 us; speedup 1.0000x reference)
//
#include <hip/hip_runtime.h>
#include <math.h>

#define NEG_INF (-__builtin_inff())

// ============================ FPS ============================
// Exact replica of reference lax.scan FPS: start at 0;
// d = min(d, ||p - p_last||^2) with numpy op order (no FMA contraction);
// argmax with first-index tie-break. One block per graph.
template<int N, int PPT, int S>
__global__ __launch_bounds__(1024) void fps_kernel(const float* __restrict__ pos,
                                                   float* __restrict__ q_out)
{
  const int b = blockIdx.x;
  const int t = threadIdx.x;
  pos += (size_t)b * N * 3;
  q_out += (size_t)b * S * 3;

  __shared__ float sx[N], sy[N], sz[N];
  __shared__ float rv[16];
  __shared__ int ri[16];
  __shared__ int s_win;

  float px[PPT], py[PPT], pz[PPT], d[PPT];
#pragma unroll
  for (int j = 0; j < PPT; ++j) {
    const int i = t * PPT + j;
    const float x = pos[3*i+0], y = pos[3*i+1], z = pos[3*i+2];
    px[j] = x; py[j] = y; pz[j] = z;
    sx[i] = x; sy[i] = y; sz[i] = z;
    d[j] = __builtin_inff();
  }
  __syncthreads();

  float lx = sx[0], ly = sy[0], lz = sz[0];
  const int lane = t & 63, wv = t >> 6;
  const int ibase = t * PPT;

  for (int it = 0; it < S; ++it) {
    if (t == 0) {
      q_out[3*it+0] = lx; q_out[3*it+1] = ly; q_out[3*it+2] = lz;
    }
    float bv = -1.0f; int bi = 0x7fffffff;
#pragma unroll
    for (int j = 0; j < PPT; ++j) {
      const float dx = __fsub_rn(px[j], lx);
      const float dy = __fsub_rn(py[j], ly);
      const float dz = __fsub_rn(pz[j], lz);
      const float nd = __fadd_rn(__fadd_rn(__fmul_rn(dx, dx), __fmul_rn(dy, dy)),
                                 __fmul_rn(dz, dz));
      const float dn = __builtin_fminf(d[j], nd);
      d[j] = dn;
      if (dn > bv) { bv = dn; bi = ibase + j; }   // ascending j: first-index tie-break
    }
    // wave (64-lane) argmax reduce, tie -> smaller index
#pragma unroll
    for (int off = 32; off > 0; off >>= 1) {
      const float ov = __shfl_down(bv, off);
      const int oi = __shfl_down(bi, off);
      if (ov > bv || (ov == bv && oi < bi)) { bv = ov; bi = oi; }
    }
    if (lane == 0) { rv[wv] = bv; ri[wv] = bi; }
    __syncthreads();
    if (wv == 0) {
      float v = (lane < 16) ? rv[lane] : -1.0f;
      int vi = (lane < 16) ? ri[lane] : 0x7fffffff;
#pragma unroll
      for (int off = 8; off > 0; off >>= 1) {
        const float ov = __shfl_down(v, off);
        const int oi = __shfl_down(vi, off);
        if (ov > v || (ov == v && oi < vi)) { v = ov; vi = oi; }
      }
      if (lane == 0) s_win = vi;
    }
    __syncthreads();
    const int wsel = s_win;
    lx = sx[wsel]; ly = sy[wsel]; lz = sz[wsel];
  }
}

// ============================ radius-KNN ============================
// Per query block: compact in-radius (d2 <= r2) candidates into LDS,
// bitonic sort u64 keys (d2 bits << 32 | idx) ascending, keep first 64.
// Matches lax.top_k(-d2, 64)'s stable K-smallest selection exactly.
#define KNN_CAP 2048

__global__ __launch_bounds__(256) void knn_kernel(const float* __restrict__ cand,
                                                  const float* __restrict__ qpos,
                                                  int nq_per_graph, int n_cand, float r2,
                                                  int* __restrict__ nbr_out,
                                                  int* __restrict__ cnt_out)
{
  const int qi = blockIdx.x;
  const int t = threadIdx.x;
  const int b = qi / nq_per_graph;
  const float* cb = cand + (size_t)b * n_cand * 3;
  const float qx = qpos[3*qi+0], qy = qpos[3*qi+1], qz = qpos[3*qi+2];

  __shared__ unsigned long long keys[KNN_CAP];
  __shared__ int s_cnt;
  if (t == 0) s_cnt = 0;
  __syncthreads();

  for (int i = t; i < n_cand; i += 256) {
    const float dx = __fsub_rn(cb[3*i+0], qx);
    const float dy = __fsub_rn(cb[3*i+1], qy);
    const float dz = __fsub_rn(cb[3*i+2], qz);
    const float d2 = __fadd_rn(__fadd_rn(__fmul_rn(dx, dx), __fmul_rn(dy, dy)),
                               __fmul_rn(dz, dz));
    if (d2 <= r2) {
      const int p = atomicAdd(&s_cnt, 1);
      if (p < KNN_CAP) keys[p] = ((unsigned long long)__float_as_uint(d2) << 32) | (unsigned)i;
    }
  }
  __syncthreads();
  const int M = min(s_cnt, KNN_CAP);
  const int out_n = min(M, 64);
  if (M > 64) {
    int P = 128; while (P < M) P <<= 1;
    for (int i = M + t; i < P; i += 256) keys[i] = ~0ULL;
    __syncthreads();
    for (int k = 2; k <= P; k <<= 1) {
      for (int j = k >> 1; j > 0; j >>= 1) {
        for (int i = t; i < P; i += 256) {
          const int l = i ^ j;
          if (l > i) {
            const unsigned long long a = keys[i], c = keys[l];
            const bool up = ((i & k) == 0);
            if ((a > c) == up) { keys[i] = c; keys[l] = a; }
          }
        }
        __syncthreads();
      }
    }
  }
  if (t < 64) nbr_out[(size_t)qi*64 + t] = (t < out_n) ? (int)(keys[t] & 0xffffffffu) : -1;
  if (t == 0) cnt_out[qi] = out_n;
}

// ============================ SA1 edge MLP (3->64->64->128) + max ============================
__global__ __launch_bounds__(256) void mlp1_kernel(const float* __restrict__ pos,
                                                   const float* __restrict__ q1,
                                                   const int* __restrict__ nbr,
                                                   const int* __restrict__ cnt_,
                                                   const float* __restrict__ W1, const float* __restrict__ b1,
                                                   const float* __restrict__ W2, const float* __restrict__ b2,
                                                   const float* __restrict__ W3, const float* __restrict__ b3,
                                                   float* __restrict__ x1)
{
  const int qi = blockIdx.x;
  const int t = threadIdx.x;
  const int bg = qi >> 12;                       // 4096 queries per graph
  const float* cb = pos + (size_t)bg * 8192 * 3;

  __shared__ float sW1[3*64];
  __shared__ float sb1[64];
  __shared__ float sW2[64*64];
  __shared__ float sb2[64];
  __shared__ float sW3[64*128];
  __shared__ float sb3[128];
  __shared__ float featT[3][64];                 // k-major rel
  __shared__ float h1[64][65];
  __shared__ float h2b[64][65];

  const int cnt = cnt_[qi];
  const float qx = q1[3*qi+0], qy = q1[3*qi+1], qz = q1[3*qi+2];

  if (t < 64) {
    float r0 = 0.f, r1 = 0.f, r2v = 0.f;
    if (t < cnt) {
      const int nb = nbr[(size_t)qi*64 + t];
      r0 = cb[3*nb+0] - qx;
      r1 = cb[3*nb+1] - qy;
      r2v = cb[3*nb+2] - qz;
    }
    featT[0][t] = r0; featT[1][t] = r1; featT[2][t] = r2v;
  }
  for (int i = t; i < 192; i += 256) sW1[i] = W1[i];
  if (t < 64) { sb1[t] = b1[t]; sb2[t] = b2[t]; }
  for (int i = t; i < 4096; i += 256) sW2[i] = W2[i];
  for (int i = t; i < 8192; i += 256) sW3[i] = W3[i];
  if (t < 128) sb3[t] = b3[t];
  __syncthreads();

  const int e = t & 63, cg = t >> 6;
  { // layer1: 16 channels per thread
    const int c0 = cg * 16;
    const float a0 = featT[0][e], a1 = featT[1][e], a2 = featT[2][e];
#pragma unroll
    for (int i = 0; i < 16; ++i) {
      float v = sb1[c0+i];
      v = fmaf(a0, sW1[0*64 + c0+i], v);
      v = fmaf(a1, sW1[1*64 + c0+i], v);
      v = fmaf(a2, sW1[2*64 + c0+i], v);
      h1[e][c0+i] = fmaxf(v, 0.f);
    }
  }
  __syncthreads();
  { // layer2
    const int c0 = cg * 16;
    float acc[16];
#pragma unroll
    for (int i = 0; i < 16; ++i) acc[i] = sb2[c0+i];
    for (int k = 0; k < 64; ++k) {
      const float a = h1[e][k];
      const float4* wp = reinterpret_cast<const float4*>(&sW2[k*64 + c0]);
#pragma unroll
      for (int i = 0; i < 4; ++i) {
        const float4 w = wp[i];
        acc[4*i+0] = fmaf(a, w.x, acc[4*i+0]);
        acc[4*i+1] = fmaf(a, w.y, acc[4*i+1]);
        acc[4*i+2] = fmaf(a, w.z, acc[4*i+2]);
        acc[4*i+3] = fmaf(a, w.w, acc[4*i+3]);
      }
    }
#pragma unroll
    for (int i = 0; i < 16; ++i) h2b[e][c0+i] = fmaxf(acc[i], 0.f);
  }
  __syncthreads();
  float acc3[32];
  const int c0h = cg * 32;
  { // layer3 (no relu)
#pragma unroll
    for (int i = 0; i < 32; ++i) acc3[i] = sb3[c0h+i];
    for (int k = 0; k < 64; ++k) {
      const float a = h2b[e][k];
      const float4* wp = reinterpret_cast<const float4*>(&sW3[k*128 + c0h]);
#pragma unroll
      for (int i = 0; i < 8; ++i) {
        const float4 w = wp[i];
        acc3[4*i+0] = fmaf(a, w.x, acc3[4*i+0]);
        acc3[4*i+1] = fmaf(a, w.y, acc3[4*i+1]);
        acc3[4*i+2] = fmaf(a, w.z, acc3[4*i+2]);
        acc3[4*i+3] = fmaf(a, w.w, acc3[4*i+3]);
      }
    }
  }
  __syncthreads();       // all reads of h1/h2b done before re-staging
  {
    const bool valid = (e < cnt);
#pragma unroll
    for (int i = 0; i < 32; ++i) {
      const float v = valid ? acc3[i] : NEG_INF;
      const int c = c0h + i;
      if (c < 64) h1[e][c] = v; else h2b[e][c-64] = v;
    }
  }
  __syncthreads();
  if (t < 128) {
    float m = NEG_INF;
    if (t < 64) {
      for (int ee = 0; ee < 64; ++ee) m = fmaxf(m, h1[ee][t]);
    } else {
      for (int ee = 0; ee < 64; ++ee) m = fmaxf(m, h2b[ee][t-64]);
    }
    x1[(size_t)qi*128 + t] = m;
  }
}

// ============================ SA2 edge MLP (131->128->128->256) + max ============================
__global__ __launch_bounds__(256) void mlp2_kernel(const float* __restrict__ q1,
                                                   const float* __restrict__ x1,
                                                   const float* __restrict__ q2,
                                                   const int* __restrict__ nbr,
                                                   const int* __restrict__ cnt_,
                                                   const float* __restrict__ W1, const float* __restrict__ b1,
                                                   const float* __restrict__ W2, const float* __restrict__ b2,
                                                   const float* __restrict__ W3, const float* __restrict__ b3,
                                                   float* __restrict__ x2)
{
  const int qi = blockIdx.x;
  const int t = threadIdx.x;
  const int bg = qi >> 10;                       // 1024 queries per graph
  const float* cb = q1 + (size_t)bg * 4096 * 3;
  const float* xb = x1 + (size_t)bg * 4096 * 128;

  __shared__ float sW[131*128];                  // staged layer weights
  __shared__ float sb[256];
  __shared__ float featT[131][64];               // k-major feat; reused as h2
  __shared__ float hbuf[64][129];                // h1; reused as h3 stage
  __shared__ int snb[64];

  const int cnt = cnt_[qi];
  const float qx = q2[3*qi+0], qy = q2[3*qi+1], qz = q2[3*qi+2];

  if (t < 64) {
    const int nb = (t < cnt) ? nbr[(size_t)qi*64 + t] : 0;
    snb[t] = nb;
    float r0 = 0.f, r1 = 0.f, r2v = 0.f;
    if (t < cnt) {
      r0 = cb[3*nb+0] - qx;
      r1 = cb[3*nb+1] - qy;
      r2v = cb[3*nb+2] - qz;
    }
    featT[128][t] = r0; featT[129][t] = r1; featT[130][t] = r2v;
  }
  for (int i = t; i < 131*128; i += 256) sW[i] = W1[i];
  if (t < 128) sb[t] = b1[t];
  __syncthreads();
  for (int idx = t; idx < 64*128; idx += 256) {   // gather x1 features
    const int e = idx >> 7, k = idx & 127;
    featT[k][e] = (e < cnt) ? xb[(size_t)snb[e]*128 + k] : 0.f;
  }
  __syncthreads();

  const int e = t & 63, cg = t >> 6, c0 = cg * 32;
  float acc[32];
  { // layer1: 131 -> 128
#pragma unroll
    for (int i = 0; i < 32; ++i) acc[i] = sb[c0+i];
    for (int k = 0; k < 131; ++k) {
      const float a = featT[k][e];
      const float4* wp = reinterpret_cast<const float4*>(&sW[k*128 + c0]);
#pragma unroll
      for (int i = 0; i < 8; ++i) {
        const float4 w = wp[i];
        acc[4*i+0] = fmaf(a, w.x, acc[4*i+0]);
        acc[4*i+1] = fmaf(a, w.y, acc[4*i+1]);
        acc[4*i+2] = fmaf(a, w.z, acc[4*i+2]);
        acc[4*i+3] = fmaf(a, w.w, acc[4*i+3]);
      }
    }
#pragma unroll
    for (int i = 0; i < 32; ++i) hbuf[e][c0+i] = fmaxf(acc[i], 0.f);
  }
  __syncthreads();
  for (int i = t; i < 128*128; i += 256) sW[i] = W2[i];
  if (t < 128) sb[t] = b2[t];
  __syncthreads();
  { // layer2: 128 -> 128 ; h2 stored k-major into featT region
#pragma unroll
    for (int i = 0; i < 32; ++i) acc[i] = sb[c0+i];
    for (int k = 0; k < 128; ++k) {
      const float a = hbuf[e][k];
      const float4* wp = reinterpret_cast<const float4*>(&sW[k*128 + c0]);
#pragma unroll
      for (int i = 0; i < 8; ++i) {
        const float4 w = wp[i];
        acc[4*i+0] = fmaf(a, w.x, acc[4*i+0]);
        acc[4*i+1] = fmaf(a, w.y, acc[4*i+1]);
        acc[4*i+2] = fmaf(a, w.z, acc[4*i+2]);
        acc[4*i+3] = fmaf(a, w.w, acc[4*i+3]);
      }
    }
  }
  __syncthreads();   // everyone done reading hbuf(h1) and sW(W2)
#pragma unroll
  for (int i = 0; i < 32; ++i) featT[c0+i][e] = fmaxf(acc[i], 0.f);
  __syncthreads();
  // layer3: 128 -> 256, in two column halves (staged W3 halves), masked max
  for (int hh = 0; hh < 2; ++hh) {
    for (int i = t; i < 128*128; i += 256) {
      const int k = i >> 7, c = i & 127;
      sW[i] = W3[k*256 + hh*128 + c];
    }
    if (t < 128) sb[t] = b3[hh*128 + t];
    __syncthreads();
#pragma unroll
    for (int i = 0; i < 32; ++i) acc[i] = sb[c0+i];
    for (int k = 0; k < 128; ++k) {
      const float a = featT[k][e];
      const float4* wp = reinterpret_cast<const float4*>(&sW[k*128 + c0]);
#pragma unroll
      for (int i = 0; i < 8; ++i) {
        const float4 w = wp[i];
        acc[4*i+0] = fmaf(a, w.x, acc[4*i+0]);
        acc[4*i+1] = fmaf(a, w.y, acc[4*i+1]);
        acc[4*i+2] = fmaf(a, w.z, acc[4*i+2]);
        acc[4*i+3] = fmaf(a, w.w, acc[4*i+3]);
      }
    }
    const bool valid = (e < cnt);
#pragma unroll
    for (int i = 0; i < 32; ++i) hbuf[e][c0+i] = valid ? acc[i] : NEG_INF;
    __syncthreads();
    if (t < 128) {
      float m = NEG_INF;
      for (int ee = 0; ee < 64; ++ee) m = fmaxf(m, hbuf[ee][t]);
      x2[(size_t)qi*256 + hh*128 + t] = m;
    }
    __syncthreads();  // hbuf reads + sW reads done before next half
  }
}

// ============================ head MLP (256->256->128->1, sigmoid) ============================
__global__ __launch_bounds__(256) void head_kernel(const float* __restrict__ x2,
                                                   const float* __restrict__ W1, const float* __restrict__ b1,
                                                   const float* __restrict__ W2, const float* __restrict__ b2,
                                                   const float* __restrict__ W3, const float* __restrict__ b3,
                                                   float* __restrict__ out)
{
  const int pt = blockIdx.x;
  const int t = threadIdx.x;
  __shared__ float sx[256];
  __shared__ float sh1[256];
  __shared__ float sh2[128];
  __shared__ float red[128];

  sx[t] = x2[(size_t)pt*256 + t];
  __syncthreads();
  float a1 = b1[t];
  for (int k = 0; k < 256; ++k) a1 = fmaf(sx[k], W1[k*256 + t], a1);
  sh1[t] = fmaxf(a1, 0.f);
  __syncthreads();
  if (t < 128) {
    float a2 = b2[t];
    for (int k = 0; k < 256; ++k) a2 = fmaf(sh1[k], W2[k*128 + t], a2);
    sh2[t] = fmaxf(a2, 0.f);
  }
  __syncthreads();
  if (t < 128) red[t] = sh2[t] * W3[t];
  __syncthreads();
  for (int o = 64; o > 0; o >>= 1) {
    if (t < o) red[t] += red[t + o];
    __syncthreads();
  }
  if (t == 0) {
    const float v = red[0] + b3[0];
    out[pt] = 1.f / (1.f + expf(-v));
  }
}

// ============================ launcher ============================
extern "C" void kernel_launch(void* const* d_in, const int* in_sizes, int n_in,
                              void* d_out, int out_size, void* d_ws, size_t ws_size,
                              hipStream_t stream)
{
  (void)in_sizes; (void)n_in; (void)out_size; (void)ws_size;
  const float* pos  = (const float*)d_in[0];
  // d_in[1] = batch (sorted, equal graphs) — layout implied, unused
  const float* s1W1 = (const float*)d_in[2];  const float* s1b1 = (const float*)d_in[3];
  const float* s1W2 = (const float*)d_in[4];  const float* s1b2 = (const float*)d_in[5];
  const float* s1W3 = (const float*)d_in[6];  const float* s1b3 = (const float*)d_in[7];
  const float* s2W1 = (const float*)d_in[8];  const float* s2b1 = (const float*)d_in[9];
  const float* s2W2 = (const float*)d_in[10]; const float* s2b2 = (const float*)d_in[11];
  const float* s2W3 = (const float*)d_in[12]; const float* s2b3 = (const float*)d_in[13];
  const float* l1W  = (const float*)d_in[14]; const float* l1b  = (const float*)d_in[15];
  const float* l2W  = (const float*)d_in[16]; const float* l2b  = (const float*)d_in[17];
  const float* l3W  = (const float*)d_in[18]; const float* l3b  = (const float*)d_in[19];
  float* out = (float*)d_out;

  char* w = (char*)d_ws;
  size_t off = 0;
  auto alloc = [&](size_t bytes) -> void* {
    void* p = w + off;
    off += (bytes + 255) & ~(size_t)255;
    return p;
  };
  float* q1   = (float*)alloc((size_t)2*4096*3*4);
  float* q2   = (float*)alloc((size_t)2*1024*3*4);
  float* x1   = (float*)alloc((size_t)8192*128*4);
  float* x2   = (float*)alloc((size_t)2048*256*4);
  int*   nbr1 = (int*)alloc((size_t)8192*64*4);
  int*   cnt1 = (int*)alloc((size_t)8192*4);
  int*   nbr2 = (int*)alloc((size_t)2048*64*4);
  int*   cnt2 = (int*)alloc((size_t)2048*4);

  const float R1SQ = (float)(0.2 * 0.2);   // mirrors Python double math -> f32
  const float R2SQ = (float)(0.4 * 0.4);

  fps_kernel<8192, 8, 4096><<<dim3(2), dim3(1024), 0, stream>>>(pos, q1);
  knn_kernel<<<dim3(8192), dim3(256), 0, stream>>>(pos, q1, 4096, 8192, R1SQ, nbr1, cnt1);
  mlp1_kernel<<<dim3(8192), dim3(256), 0, stream>>>(pos, q1, nbr1, cnt1,
                                                    s1W1, s1b1, s1W2, s1b2, s1W3, s1b3, x1);
  fps_kernel<4096, 4, 1024><<<dim3(2), dim3(1024), 0, stream>>>(q1, q2);
  knn_kernel<<<dim3(2048), dim3(256), 0, stream>>>(q1, q2, 1024, 4096, R2SQ, nbr2, cnt2);
  mlp2_kernel<<<dim3(2048), dim3(256), 0, stream>>>(q1, x1, q2, nbr2, cnt2,
                                                    s2W1, s2b1, s2W2, s2b2, s2W3, s2b3, x2);
  head_kernel<<<dim3(2048), dim3(256), 0, stream>>>(x2, l1W, l1b, l2W, l2b, l3W, l3b, out);
}

// Round 2
// 8259.377 us; speedup vs baseline: 1.1578x; 1.1578x over previous
//
#include <hip/hip_runtime.h>
#include <math.h>

#define NEG_INF (-__builtin_inff())
#define POS_INF (__builtin_inff())

// ===================== DPP helpers (wave64 max-reduce) =====================
__device__ __forceinline__ int imax_i(int a, int b) { return a > b ? a : b; }

template<int CTRL, int RMASK>
__device__ __forceinline__ int dpp_max_step(int y) {
  const int t = __builtin_amdgcn_update_dpp(y, y, CTRL, RMASK, 0xf, false);
  return imax_i(y, t);
}

// ============================ FPS (pruned, exact) ============================
// Bit-exact replica of reference lax.scan FPS:
//   q[it] = pts[last]; d = min(d, ||p - pts[last]||^2) (numpy op order, no FMA);
//   next = argmax(d) with first-ORIGINAL-index tie-break.
// Acceleration (result-invariant):
//  - Morton-cell counting sort -> each thread owns PPT spatially-compact points
//    (registers) with bbox; skip chunk when bboxMinDist^2*0.99999 >= cached
//    chunk max (safe: computed nd >= mind2*(1-8eps), so min(d,nd) unchanged).
//  - wave argmax via DPP (int bits of d^2 >= 0 are order-monotone), tie ->
//    min orig via ballot; block combine via packed u64 (val<<32 | ~orig),
//    double-buffered slots -> ONE barrier per iteration.
template<int N, int PPT, int S>
__global__ __launch_bounds__(1024) void fpsp_kernel(const float* __restrict__ pos,
                                                    float* __restrict__ q_out)
{
  constexpr int NT = 1024;
  constexpr int NW = NT / 64;
  constexpr int CELLS = 4096;     // 16^3 Morton cells
  constexpr int CPT = CELLS / NT; // 4
  static_assert(N == NT * PPT, "chunking");

  const int b = blockIdx.x;
  const int t = threadIdx.x;
  pos += (size_t)b * N * 3;
  q_out += (size_t)b * S * 3;

  __shared__ float sx[N], sy[N], sz[N];     // ORIGINAL-index order
  __shared__ int sorder[N];                  // slot -> orig
  __shared__ int hist[CELLS];
  __shared__ int scanbuf[NT];
  __shared__ unsigned long long wbuf[2][NW];

  // ---- load coords + cell histogram ----
  for (int i = t; i < CELLS; i += NT) hist[i] = 0;
  __syncthreads();
  for (int i = t; i < N; i += NT) {
    const float x = pos[3*i+0], y = pos[3*i+1], z = pos[3*i+2];
    sx[i] = x; sy[i] = y; sz[i] = z;
    int cx = (int)(x * 16.f); cx = cx < 0 ? 0 : (cx > 15 ? 15 : cx);
    int cy = (int)(y * 16.f); cy = cy < 0 ? 0 : (cy > 15 ? 15 : cy);
    int cz = (int)(z * 16.f); cz = cz < 0 ? 0 : (cz > 15 ? 15 : cz);
    int m = 0;
#pragma unroll
    for (int k = 0; k < 4; ++k)
      m |= (((cx >> k) & 1) << (3*k+2)) | (((cy >> k) & 1) << (3*k+1)) | (((cz >> k) & 1) << (3*k));
    atomicAdd(&hist[m], 1);
  }
  __syncthreads();
  // ---- exclusive scan of hist ----
  int loc[CPT]; int run = 0;
#pragma unroll
  for (int j = 0; j < CPT; ++j) { loc[j] = run; run += hist[t*CPT + j]; }
  scanbuf[t] = run;
  __syncthreads();
  for (int off = 1; off < NT; off <<= 1) {
    const int o = (t >= off) ? scanbuf[t - off] : 0;
    __syncthreads();
    scanbuf[t] += o;
    __syncthreads();
  }
  const int base = scanbuf[t] - run;   // exclusive block offset
#pragma unroll
  for (int j = 0; j < CPT; ++j) hist[t*CPT + j] = base + loc[j];
  __syncthreads();
  // ---- scatter (slot -> orig) ----
  for (int i = t; i < N; i += NT) {
    const float x = sx[i], y = sy[i], z = sz[i];
    int cx = (int)(x * 16.f); cx = cx < 0 ? 0 : (cx > 15 ? 15 : cx);
    int cy = (int)(y * 16.f); cy = cy < 0 ? 0 : (cy > 15 ? 15 : cy);
    int cz = (int)(z * 16.f); cz = cz < 0 ? 0 : (cz > 15 ? 15 : cz);
    int m = 0;
#pragma unroll
    for (int k = 0; k < 4; ++k)
      m |= (((cx >> k) & 1) << (3*k+2)) | (((cy >> k) & 1) << (3*k+1)) | (((cz >> k) & 1) << (3*k));
    const int slot = atomicAdd(&hist[m], 1);
    sorder[slot] = i;
  }
  __syncthreads();
  // ---- gather chunk into registers + bbox ----
  float px[PPT], py[PPT], pz[PPT], d[PPT];
  int og[PPT];
  float bxmin = POS_INF, bxmax = NEG_INF, bymin = POS_INF, bymax = NEG_INF,
        bzmin = POS_INF, bzmax = NEG_INF;
#pragma unroll
  for (int j = 0; j < PPT; ++j) {
    const int o = sorder[t*PPT + j];
    og[j] = o;
    const float x = sx[o], y = sy[o], z = sz[o];
    px[j] = x; py[j] = y; pz[j] = z;
    bxmin = fminf(bxmin, x); bxmax = fmaxf(bxmax, x);
    bymin = fminf(bymin, y); bymax = fmaxf(bymax, y);
    bzmin = fminf(bzmin, z); bzmax = fmaxf(bzmax, z);
    d[j] = POS_INF;
  }

  float cval = POS_INF;      // cached chunk max (inf -> force first recompute)
  int corig = 0x7fffffff;    // cached arg (orig idx)

  float lx = sx[0], ly = sy[0], lz = sz[0];
  int p = 0;

  for (int it = 0; it < S; ++it) {
    if (t == 0) { q_out[3*it+0] = lx; q_out[3*it+1] = ly; q_out[3*it+2] = lz; }

    // conservative bbox min dist^2 to (lx,ly,lz)
    const float ddx = fmaxf(0.f, fmaxf(bxmin - lx, lx - bxmax));
    const float ddy = fmaxf(0.f, fmaxf(bymin - ly, ly - bymax));
    const float ddz = fmaxf(0.f, fmaxf(bzmin - lz, lz - bzmax));
    const float mind2 = ddx*ddx + ddy*ddy + ddz*ddz;
    if (!(mind2 * 0.99999f >= cval)) {
      float bv = -1.f; int bo = 0x7fffffff;
#pragma unroll
      for (int j = 0; j < PPT; ++j) {
        const float dx = __fsub_rn(px[j], lx);
        const float dy = __fsub_rn(py[j], ly);
        const float dz = __fsub_rn(pz[j], lz);
        const float nd = __fadd_rn(__fadd_rn(__fmul_rn(dx, dx), __fmul_rn(dy, dy)),
                                   __fmul_rn(dz, dz));
        const float dn = __builtin_fminf(d[j], nd);
        d[j] = dn;
        if (dn > bv || (dn == bv && og[j] < bo)) { bv = dn; bo = og[j]; }
      }
      cval = bv; corig = bo;
    }

    // ---- wave64 max via DPP on int bits (cval >= 0) ----
    const int x = __float_as_int(cval);
    int y = x;
    y = dpp_max_step<0x111, 0xf>(y);  // row_shr:1
    y = dpp_max_step<0x112, 0xf>(y);  // row_shr:2
    y = dpp_max_step<0x114, 0xf>(y);  // row_shr:4
    y = dpp_max_step<0x118, 0xf>(y);  // row_shr:8
    y = dpp_max_step<0x142, 0xa>(y);  // row_bcast:15 -> rows 1,3
    y = dpp_max_step<0x143, 0xc>(y);  // row_bcast:31 -> rows 2,3
    const int mb = __builtin_amdgcn_readlane(y, 63);
    unsigned long long eq = __ballot(x == mb);
    int wo = 0x7fffffff;
    while (eq) {                       // usually a single iteration
      const int l = __builtin_ctzll(eq);
      const int o = __builtin_amdgcn_readlane(corig, l);
      wo = wo < o ? wo : o;
      eq &= eq - 1;
    }
    if ((t & 63) == 0)
      wbuf[p][t >> 6] = ((unsigned long long)(unsigned)mb << 32) |
                        (unsigned)(0xFFFFFFFFu - (unsigned)wo);
    __syncthreads();
    // ---- block combine: every thread reads NW slots (broadcast) ----
    unsigned long long wm = wbuf[p][0];
#pragma unroll
    for (int i = 1; i < NW; ++i) {
      const unsigned long long v = wbuf[p][i];
      wm = v > wm ? v : wm;
    }
    const int worig = (int)(0xFFFFFFFFu - (unsigned)(wm & 0xFFFFFFFFu));
    lx = sx[worig]; ly = sy[worig]; lz = sz[worig];
    p ^= 1;
  }
}

// ============================ radius-KNN ============================
#define KNN_CAP 2048

__global__ __launch_bounds__(256) void knn_kernel(const float* __restrict__ cand,
                                                  const float* __restrict__ qpos,
                                                  int nq_per_graph, int n_cand, float r2,
                                                  int* __restrict__ nbr_out,
                                                  int* __restrict__ cnt_out)
{
  const int qi = blockIdx.x;
  const int t = threadIdx.x;
  const int b = qi / nq_per_graph;
  const float* cb = cand + (size_t)b * n_cand * 3;
  const float qx = qpos[3*qi+0], qy = qpos[3*qi+1], qz = qpos[3*qi+2];

  __shared__ unsigned long long keys[KNN_CAP];
  __shared__ int s_cnt;
  if (t == 0) s_cnt = 0;
  __syncthreads();

  for (int i = t; i < n_cand; i += 256) {
    const float dx = __fsub_rn(cb[3*i+0], qx);
    const float dy = __fsub_rn(cb[3*i+1], qy);
    const float dz = __fsub_rn(cb[3*i+2], qz);
    const float d2 = __fadd_rn(__fadd_rn(__fmul_rn(dx, dx), __fmul_rn(dy, dy)),
                               __fmul_rn(dz, dz));
    if (d2 <= r2) {
      const int p = atomicAdd(&s_cnt, 1);
      if (p < KNN_CAP) keys[p] = ((unsigned long long)__float_as_uint(d2) << 32) | (unsigned)i;
    }
  }
  __syncthreads();
  const int M = min(s_cnt, KNN_CAP);
  const int out_n = min(M, 64);
  if (M > 64) {
    int P = 128; while (P < M) P <<= 1;
    for (int i = M + t; i < P; i += 256) keys[i] = ~0ULL;
    __syncthreads();
    for (int k = 2; k <= P; k <<= 1) {
      for (int j = k >> 1; j > 0; j >>= 1) {
        for (int i = t; i < P; i += 256) {
          const int l = i ^ j;
          if (l > i) {
            const unsigned long long a = keys[i], c = keys[l];
            const bool up = ((i & k) == 0);
            if ((a > c) == up) { keys[i] = c; keys[l] = a; }
          }
        }
        __syncthreads();
      }
    }
  }
  if (t < 64) nbr_out[(size_t)qi*64 + t] = (t < out_n) ? (int)(keys[t] & 0xffffffffu) : -1;
  if (t == 0) cnt_out[qi] = out_n;
}

// ============================ SA1 edge MLP (3->64->64->128) + max ============================
__global__ __launch_bounds__(256) void mlp1_kernel(const float* __restrict__ pos,
                                                   const float* __restrict__ q1,
                                                   const int* __restrict__ nbr,
                                                   const int* __restrict__ cnt_,
                                                   const float* __restrict__ W1, const float* __restrict__ b1,
                                                   const float* __restrict__ W2, const float* __restrict__ b2,
                                                   const float* __restrict__ W3, const float* __restrict__ b3,
                                                   float* __restrict__ x1)
{
  const int qi = blockIdx.x;
  const int t = threadIdx.x;
  const int bg = qi >> 12;                       // 4096 queries per graph
  const float* cb = pos + (size_t)bg * 8192 * 3;

  __shared__ float sW1[3*64];
  __shared__ float sb1[64];
  __shared__ float sW2[64*64];
  __shared__ float sb2[64];
  __shared__ float sW3[64*128];
  __shared__ float sb3[128];
  __shared__ float featT[3][64];                 // k-major rel
  __shared__ float h1[64][65];
  __shared__ float h2b[64][65];

  const int cnt = cnt_[qi];
  const float qx = q1[3*qi+0], qy = q1[3*qi+1], qz = q1[3*qi+2];

  if (t < 64) {
    float r0 = 0.f, r1 = 0.f, r2v = 0.f;
    if (t < cnt) {
      const int nb = nbr[(size_t)qi*64 + t];
      r0 = cb[3*nb+0] - qx;
      r1 = cb[3*nb+1] - qy;
      r2v = cb[3*nb+2] - qz;
    }
    featT[0][t] = r0; featT[1][t] = r1; featT[2][t] = r2v;
  }
  for (int i = t; i < 192; i += 256) sW1[i] = W1[i];
  if (t < 64) { sb1[t] = b1[t]; sb2[t] = b2[t]; }
  for (int i = t; i < 4096; i += 256) sW2[i] = W2[i];
  for (int i = t; i < 8192; i += 256) sW3[i] = W3[i];
  if (t < 128) sb3[t] = b3[t];
  __syncthreads();

  const int e = t & 63, cg = t >> 6;
  { // layer1: 16 channels per thread
    const int c0 = cg * 16;
    const float a0 = featT[0][e], a1 = featT[1][e], a2 = featT[2][e];
#pragma unroll
    for (int i = 0; i < 16; ++i) {
      float v = sb1[c0+i];
      v = fmaf(a0, sW1[0*64 + c0+i], v);
      v = fmaf(a1, sW1[1*64 + c0+i], v);
      v = fmaf(a2, sW1[2*64 + c0+i], v);
      h1[e][c0+i] = fmaxf(v, 0.f);
    }
  }
  __syncthreads();
  { // layer2
    const int c0 = cg * 16;
    float acc[16];
#pragma unroll
    for (int i = 0; i < 16; ++i) acc[i] = sb2[c0+i];
    for (int k = 0; k < 64; ++k) {
      const float a = h1[e][k];
      const float4* wp = reinterpret_cast<const float4*>(&sW2[k*64 + c0]);
#pragma unroll
      for (int i = 0; i < 4; ++i) {
        const float4 w = wp[i];
        acc[4*i+0] = fmaf(a, w.x, acc[4*i+0]);
        acc[4*i+1] = fmaf(a, w.y, acc[4*i+1]);
        acc[4*i+2] = fmaf(a, w.z, acc[4*i+2]);
        acc[4*i+3] = fmaf(a, w.w, acc[4*i+3]);
      }
    }
#pragma unroll
    for (int i = 0; i < 16; ++i) h2b[e][c0+i] = fmaxf(acc[i], 0.f);
  }
  __syncthreads();
  float acc3[32];
  const int c0h = cg * 32;
  { // layer3 (no relu)
#pragma unroll
    for (int i = 0; i < 32; ++i) acc3[i] = sb3[c0h+i];
    for (int k = 0; k < 64; ++k) {
      const float a = h2b[e][k];
      const float4* wp = reinterpret_cast<const float4*>(&sW3[k*128 + c0h]);
#pragma unroll
      for (int i = 0; i < 8; ++i) {
        const float4 w = wp[i];
        acc3[4*i+0] = fmaf(a, w.x, acc3[4*i+0]);
        acc3[4*i+1] = fmaf(a, w.y, acc3[4*i+1]);
        acc3[4*i+2] = fmaf(a, w.z, acc3[4*i+2]);
        acc3[4*i+3] = fmaf(a, w.w, acc3[4*i+3]);
      }
    }
  }
  __syncthreads();       // all reads of h1/h2b done before re-staging
  {
    const bool valid = (e < cnt);
#pragma unroll
    for (int i = 0; i < 32; ++i) {
      const float v = valid ? acc3[i] : NEG_INF;
      const int c = c0h + i;
      if (c < 64) h1[e][c] = v; else h2b[e][c-64] = v;
    }
  }
  __syncthreads();
  if (t < 128) {
    float m = NEG_INF;
    if (t < 64) {
      for (int ee = 0; ee < 64; ++ee) m = fmaxf(m, h1[ee][t]);
    } else {
      for (int ee = 0; ee < 64; ++ee) m = fmaxf(m, h2b[ee][t-64]);
    }
    x1[(size_t)qi*128 + t] = m;
  }
}

// ============================ SA2 edge MLP (131->128->128->256) + max ============================
__global__ __launch_bounds__(256) void mlp2_kernel(const float* __restrict__ q1,
                                                   const float* __restrict__ x1,
                                                   const float* __restrict__ q2,
                                                   const int* __restrict__ nbr,
                                                   const int* __restrict__ cnt_,
                                                   const float* __restrict__ W1, const float* __restrict__ b1,
                                                   const float* __restrict__ W2, const float* __restrict__ b2,
                                                   const float* __restrict__ W3, const float* __restrict__ b3,
                                                   float* __restrict__ x2)
{
  const int qi = blockIdx.x;
  const int t = threadIdx.x;
  const int bg = qi >> 10;                       // 1024 queries per graph
  const float* cb = q1 + (size_t)bg * 4096 * 3;
  const float* xb = x1 + (size_t)bg * 4096 * 128;

  __shared__ float sW[131*128];                  // staged layer weights
  __shared__ float sb[256];
  __shared__ float featT[131][64];               // k-major feat; reused as h2
  __shared__ float hbuf[64][129];                // h1; reused as h3 stage
  __shared__ int snb[64];

  const int cnt = cnt_[qi];
  const float qx = q2[3*qi+0], qy = q2[3*qi+1], qz = q2[3*qi+2];

  if (t < 64) {
    const int nb = (t < cnt) ? nbr[(size_t)qi*64 + t] : 0;
    snb[t] = nb;
    float r0 = 0.f, r1 = 0.f, r2v = 0.f;
    if (t < cnt) {
      r0 = cb[3*nb+0] - qx;
      r1 = cb[3*nb+1] - qy;
      r2v = cb[3*nb+2] - qz;
    }
    featT[128][t] = r0; featT[129][t] = r1; featT[130][t] = r2v;
  }
  for (int i = t; i < 131*128; i += 256) sW[i] = W1[i];
  if (t < 128) sb[t] = b1[t];
  __syncthreads();
  for (int idx = t; idx < 64*128; idx += 256) {   // gather x1 features
    const int e = idx >> 7, k = idx & 127;
    featT[k][e] = (e < cnt) ? xb[(size_t)snb[e]*128 + k] : 0.f;
  }
  __syncthreads();

  const int e = t & 63, cg = t >> 6, c0 = cg * 32;
  float acc[32];
  { // layer1: 131 -> 128
#pragma unroll
    for (int i = 0; i < 32; ++i) acc[i] = sb[c0+i];
    for (int k = 0; k < 131; ++k) {
      const float a = featT[k][e];
      const float4* wp = reinterpret_cast<const float4*>(&sW[k*128 + c0]);
#pragma unroll
      for (int i = 0; i < 8; ++i) {
        const float4 w = wp[i];
        acc[4*i+0] = fmaf(a, w.x, acc[4*i+0]);
        acc[4*i+1] = fmaf(a, w.y, acc[4*i+1]);
        acc[4*i+2] = fmaf(a, w.z, acc[4*i+2]);
        acc[4*i+3] = fmaf(a, w.w, acc[4*i+3]);
      }
    }
#pragma unroll
    for (int i = 0; i < 32; ++i) hbuf[e][c0+i] = fmaxf(acc[i], 0.f);
  }
  __syncthreads();
  for (int i = t; i < 128*128; i += 256) sW[i] = W2[i];
  if (t < 128) sb[t] = b2[t];
  __syncthreads();
  { // layer2: 128 -> 128 ; h2 stored k-major into featT region
#pragma unroll
    for (int i = 0; i < 32; ++i) acc[i] = sb[c0+i];
    for (int k = 0; k < 128; ++k) {
      const float a = hbuf[e][k];
      const float4* wp = reinterpret_cast<const float4*>(&sW[k*128 + c0]);
#pragma unroll
      for (int i = 0; i < 8; ++i) {
        const float4 w = wp[i];
        acc[4*i+0] = fmaf(a, w.x, acc[4*i+0]);
        acc[4*i+1] = fmaf(a, w.y, acc[4*i+1]);
        acc[4*i+2] = fmaf(a, w.z, acc[4*i+2]);
        acc[4*i+3] = fmaf(a, w.w, acc[4*i+3]);
      }
    }
  }
  __syncthreads();   // everyone done reading hbuf(h1) and sW(W2)
#pragma unroll
  for (int i = 0; i < 32; ++i) featT[c0+i][e] = fmaxf(acc[i], 0.f);
  __syncthreads();
  // layer3: 128 -> 256, in two column halves (staged W3 halves), masked max
  for (int hh = 0; hh < 2; ++hh) {
    for (int i = t; i < 128*128; i += 256) {
      const int k = i >> 7, c = i & 127;
      sW[i] = W3[k*256 + hh*128 + c];
    }
    if (t < 128) sb[t] = b3[hh*128 + t];
    __syncthreads();
#pragma unroll
    for (int i = 0; i < 32; ++i) acc[i] = sb[c0+i];
    for (int k = 0; k < 128; ++k) {
      const float a = featT[k][e];
      const float4* wp = reinterpret_cast<const float4*>(&sW[k*128 + c0]);
#pragma unroll
      for (int i = 0; i < 8; ++i) {
        const float4 w = wp[i];
        acc[4*i+0] = fmaf(a, w.x, acc[4*i+0]);
        acc[4*i+1] = fmaf(a, w.y, acc[4*i+1]);
        acc[4*i+2] = fmaf(a, w.z, acc[4*i+2]);
        acc[4*i+3] = fmaf(a, w.w, acc[4*i+3]);
      }
    }
    const bool valid = (e < cnt);
#pragma unroll
    for (int i = 0; i < 32; ++i) hbuf[e][c0+i] = valid ? acc[i] : NEG_INF;
    __syncthreads();
    if (t < 128) {
      float m = NEG_INF;
      for (int ee = 0; ee < 64; ++ee) m = fmaxf(m, hbuf[ee][t]);
      x2[(size_t)qi*256 + hh*128 + t] = m;
    }
    __syncthreads();  // hbuf reads + sW reads done before next half
  }
}

// ============================ head MLP (256->256->128->1, sigmoid) ============================
__global__ __launch_bounds__(256) void head_kernel(const float* __restrict__ x2,
                                                   const float* __restrict__ W1, const float* __restrict__ b1,
                                                   const float* __restrict__ W2, const float* __restrict__ b2,
                                                   const float* __restrict__ W3, const float* __restrict__ b3,
                                                   float* __restrict__ out)
{
  const int pt = blockIdx.x;
  const int t = threadIdx.x;
  __shared__ float sx[256];
  __shared__ float sh1[256];
  __shared__ float sh2[128];
  __shared__ float red[128];

  sx[t] = x2[(size_t)pt*256 + t];
  __syncthreads();
  float a1 = b1[t];
  for (int k = 0; k < 256; ++k) a1 = fmaf(sx[k], W1[k*256 + t], a1);
  sh1[t] = fmaxf(a1, 0.f);
  __syncthreads();
  if (t < 128) {
    float a2 = b2[t];
    for (int k = 0; k < 256; ++k) a2 = fmaf(sh1[k], W2[k*128 + t], a2);
    sh2[t] = fmaxf(a2, 0.f);
  }
  __syncthreads();
  if (t < 128) red[t] = sh2[t] * W3[t];
  __syncthreads();
  for (int o = 64; o > 0; o >>= 1) {
    if (t < o) red[t] += red[t + o];
    __syncthreads();
  }
  if (t == 0) {
    const float v = red[0] + b3[0];
    out[pt] = 1.f / (1.f + expf(-v));
  }
}

// ============================ launcher ============================
extern "C" void kernel_launch(void* const* d_in, const int* in_sizes, int n_in,
                              void* d_out, int out_size, void* d_ws, size_t ws_size,
                              hipStream_t stream)
{
  (void)in_sizes; (void)n_in; (void)out_size; (void)ws_size;
  const float* pos  = (const float*)d_in[0];
  // d_in[1] = batch (sorted, equal graphs) — layout implied, unused
  const float* s1W1 = (const float*)d_in[2];  const float* s1b1 = (const float*)d_in[3];
  const float* s1W2 = (const float*)d_in[4];  const float* s1b2 = (const float*)d_in[5];
  const float* s1W3 = (const float*)d_in[6];  const float* s1b3 = (const float*)d_in[7];
  const float* s2W1 = (const float*)d_in[8];  const float* s2b1 = (const float*)d_in[9];
  const float* s2W2 = (const float*)d_in[10]; const float* s2b2 = (const float*)d_in[11];
  const float* s2W3 = (const float*)d_in[12]; const float* s2b3 = (const float*)d_in[13];
  const float* l1W  = (const float*)d_in[14]; const float* l1b  = (const float*)d_in[15];
  const float* l2W  = (const float*)d_in[16]; const float* l2b  = (const float*)d_in[17];
  const float* l3W  = (const float*)d_in[18]; const float* l3b  = (const float*)d_in[19];
  float* out = (float*)d_out;

  char* w = (char*)d_ws;
  size_t off = 0;
  auto alloc = [&](size_t bytes) -> void* {
    void* p = w + off;
    off += (bytes + 255) & ~(size_t)255;
    return p;
  };
  float* q1   = (float*)alloc((size_t)2*4096*3*4);
  float* q2   = (float*)alloc((size_t)2*1024*3*4);
  float* x1   = (float*)alloc((size_t)8192*128*4);
  float* x2   = (float*)alloc((size_t)2048*256*4);
  int*   nbr1 = (int*)alloc((size_t)8192*64*4);
  int*   cnt1 = (int*)alloc((size_t)8192*4);
  int*   nbr2 = (int*)alloc((size_t)2048*64*4);
  int*   cnt2 = (int*)alloc((size_t)2048*4);

  const float R1SQ = (float)(0.2 * 0.2);   // mirrors Python double math -> f32
  const float R2SQ = (float)(0.4 * 0.4);

  fpsp_kernel<8192, 8, 4096><<<dim3(2), dim3(1024), 0, stream>>>(pos, q1);
  knn_kernel<<<dim3(8192), dim3(256), 0, stream>>>(pos, q1, 4096, 8192, R1SQ, nbr1, cnt1);
  mlp1_kernel<<<dim3(8192), dim3(256), 0, stream>>>(pos, q1, nbr1, cnt1,
                                                    s1W1, s1b1, s1W2, s1b2, s1W3, s1b3, x1);
  fpsp_kernel<4096, 4, 1024><<<dim3(2), dim3(1024), 0, stream>>>(q1, q2);
  knn_kernel<<<dim3(2048), dim3(256), 0, stream>>>(q1, q2, 1024, 4096, R2SQ, nbr2, cnt2);
  mlp2_kernel<<<dim3(2048), dim3(256), 0, stream>>>(q1, x1, q2, nbr2, cnt2,
                                                    s2W1, s2b1, s2W2, s2b2, s2W3, s2b3, x2);
  head_kernel<<<dim3(2048), dim3(256), 0, stream>>>(x2, l1W, l1b, l2W, l2b, l3W, l3b, out);
}

// Round 3
// 7414.260 us; speedup vs baseline: 1.2898x; 1.1140x over previous
//
#include <hip/hip_runtime.h>
#include <math.h>

#define NEG_INF (-__builtin_inff())
#define POS_INF (__builtin_inff())

// ===================== DPP u64 max helpers (wave64) =====================
__device__ __forceinline__ unsigned long long u64max(unsigned long long a,
                                                     unsigned long long b) {
  return a > b ? a : b;
}

template<int CTRL, int RMASK>
__device__ __forceinline__ unsigned long long dpp_u64max_step(unsigned long long y) {
  const int lo = (int)(unsigned)(y & 0xffffffffULL);
  const int hi = (int)(unsigned)(y >> 32);
  const int tlo = __builtin_amdgcn_update_dpp(lo, lo, CTRL, RMASK, 0xf, false);
  const int thi = __builtin_amdgcn_update_dpp(hi, hi, CTRL, RMASK, 0xf, false);
  const unsigned long long t =
      ((unsigned long long)(unsigned)thi << 32) | (unsigned)tlo;
  return u64max(y, t);
}

// ============================ FPS (pruned, exact) ============================
// Bit-exact replica of reference lax.scan FPS:
//   q[it] = pts[last]; d = min(d, ||p - pts[last]||^2) (numpy op order, no FMA);
//   next = argmax(d) with first-ORIGINAL-index tie-break.
// Acceleration (result-invariant):
//  - Morton-cell counting sort -> each thread owns PPT spatially-compact points
//    (registers) with bbox; skip chunk when bboxMinDist^2*0.99999 >= cached
//    chunk max (safe: computed nd >= mind2*(1-8eps), so min(d,nd) unchanged,
//    hence d[], cached max, and cached argmax all stay exact).
//  - wave argmax: packed u64 (valbits<<32 | ~orig) DPP max chain -> lane 63.
//  - block combine: lane reads slot (lane&7) (broadcast), 3x DPP row_ror
//    u64-max (rotation mod 8 within row16 covers all 8 slots).
//  - NO global stores in the loop (winner indices to LDS; q_out written once
//    at the end) -> no vmcnt(0) drain at the per-iteration barrier.
//  - double-buffered slot array -> ONE barrier per iteration.
template<int N, int PPT, int S>
__global__ __launch_bounds__(512) void fpsp_kernel(const float* __restrict__ pos,
                                                   float* __restrict__ q_out)
{
  constexpr int NT = 512;
  constexpr int NW = NT / 64;      // 8 waves
  constexpr int CELLS = 4096;      // 16^3 Morton cells
  constexpr int CPT = CELLS / NT;  // 8
  static_assert(N == NT * PPT, "chunking");
  static_assert(S <= CELLS, "winner list fits in hist");

  const int b = blockIdx.x;
  const int t = threadIdx.x;
  pos += (size_t)b * N * 3;
  q_out += (size_t)b * S * 3;

  __shared__ float sx[N], sy[N], sz[N];      // ORIGINAL-index order
  __shared__ int sorder[N];                  // slot -> orig
  __shared__ int hist[CELLS];                // reused as winner list after setup
  __shared__ int scanbuf[NT];
  __shared__ unsigned long long wbuf[2][NW];

  int* const swin = hist;                    // alias: setup-only vs loop-only

  // ---- load coords + cell histogram ----
  for (int i = t; i < CELLS; i += NT) hist[i] = 0;
  __syncthreads();
  for (int i = t; i < N; i += NT) {
    const float x = pos[3*i+0], y = pos[3*i+1], z = pos[3*i+2];
    sx[i] = x; sy[i] = y; sz[i] = z;
    int cx = (int)(x * 16.f); cx = cx < 0 ? 0 : (cx > 15 ? 15 : cx);
    int cy = (int)(y * 16.f); cy = cy < 0 ? 0 : (cy > 15 ? 15 : cy);
    int cz = (int)(z * 16.f); cz = cz < 0 ? 0 : (cz > 15 ? 15 : cz);
    int m = 0;
#pragma unroll
    for (int k = 0; k < 4; ++k)
      m |= (((cx >> k) & 1) << (3*k+2)) | (((cy >> k) & 1) << (3*k+1)) | (((cz >> k) & 1) << (3*k));
    atomicAdd(&hist[m], 1);
  }
  __syncthreads();
  // ---- exclusive scan of hist ----
  int loc[CPT]; int run = 0;
#pragma unroll
  for (int j = 0; j < CPT; ++j) { loc[j] = run; run += hist[t*CPT + j]; }
  scanbuf[t] = run;
  __syncthreads();
  for (int off = 1; off < NT; off <<= 1) {
    const int o = (t >= off) ? scanbuf[t - off] : 0;
    __syncthreads();
    scanbuf[t] += o;
    __syncthreads();
  }
  const int base = scanbuf[t] - run;   // exclusive block offset
#pragma unroll
  for (int j = 0; j < CPT; ++j) hist[t*CPT + j] = base + loc[j];
  __syncthreads();
  // ---- scatter (slot -> orig) ----
  for (int i = t; i < N; i += NT) {
    const float x = sx[i], y = sy[i], z = sz[i];
    int cx = (int)(x * 16.f); cx = cx < 0 ? 0 : (cx > 15 ? 15 : cx);
    int cy = (int)(y * 16.f); cy = cy < 0 ? 0 : (cy > 15 ? 15 : cy);
    int cz = (int)(z * 16.f); cz = cz < 0 ? 0 : (cz > 15 ? 15 : cz);
    int m = 0;
#pragma unroll
    for (int k = 0; k < 4; ++k)
      m |= (((cx >> k) & 1) << (3*k+2)) | (((cy >> k) & 1) << (3*k+1)) | (((cz >> k) & 1) << (3*k));
    const int slot = atomicAdd(&hist[m], 1);
    sorder[slot] = i;
  }
  __syncthreads();
  // ---- gather chunk into registers + bbox ----
  float px[PPT], py[PPT], pz[PPT], d[PPT];
  int og[PPT];
  float bxmin = POS_INF, bxmax = NEG_INF, bymin = POS_INF, bymax = NEG_INF,
        bzmin = POS_INF, bzmax = NEG_INF;
#pragma unroll
  for (int j = 0; j < PPT; ++j) {
    const int o = sorder[t*PPT + j];
    og[j] = o;
    const float x = sx[o], y = sy[o], z = sz[o];
    px[j] = x; py[j] = y; pz[j] = z;
    bxmin = fminf(bxmin, x); bxmax = fmaxf(bxmax, x);
    bymin = fminf(bymin, y); bymax = fmaxf(bymax, y);
    bzmin = fminf(bzmin, z); bzmax = fmaxf(bzmax, z);
    d[j] = POS_INF;
  }
  __syncthreads();   // hist fully consumed (sorder reads done) before swin reuse

  float cval = POS_INF;      // cached chunk max (inf -> force first recompute)
  int corig = 0x7fffffff;    // cached arg (orig idx)

  int worig = 0;             // first selected point = index 0
  int p = 0;

  for (int it = 0; it < S; ++it) {
    if (t == 0) swin[it] = worig;
    const float lx = sx[worig], ly = sy[worig], lz = sz[worig];

    // conservative bbox min dist^2 to (lx,ly,lz)
    const float ddx = fmaxf(0.f, fmaxf(bxmin - lx, lx - bxmax));
    const float ddy = fmaxf(0.f, fmaxf(bymin - ly, ly - bymax));
    const float ddz = fmaxf(0.f, fmaxf(bzmin - lz, lz - bzmax));
    const float mind2 = ddx*ddx + ddy*ddy + ddz*ddz;
    if (!(mind2 * 0.99999f >= cval)) {
      float bv = -1.f; int bo = 0x7fffffff;
#pragma unroll
      for (int j = 0; j < PPT; ++j) {
        const float dx = __fsub_rn(px[j], lx);
        const float dy = __fsub_rn(py[j], ly);
        const float dz = __fsub_rn(pz[j], lz);
        const float nd = __fadd_rn(__fadd_rn(__fmul_rn(dx, dx), __fmul_rn(dy, dy)),
                                   __fmul_rn(dz, dz));
        const float dn = __builtin_fminf(d[j], nd);
        d[j] = dn;
        if (dn > bv || (dn == bv && og[j] < bo)) { bv = dn; bo = og[j]; }
      }
      cval = bv; corig = bo;
    }

    // ---- wave64 packed u64 max via DPP; result lands in lane 63 ----
    unsigned long long y =
        ((unsigned long long)(unsigned)__float_as_int(cval) << 32) |
        (unsigned)~(unsigned)corig;
    y = dpp_u64max_step<0x111, 0xf>(y);  // row_shr:1
    y = dpp_u64max_step<0x112, 0xf>(y);  // row_shr:2
    y = dpp_u64max_step<0x114, 0xf>(y);  // row_shr:4
    y = dpp_u64max_step<0x118, 0xf>(y);  // row_shr:8
    y = dpp_u64max_step<0x142, 0xa>(y);  // row_bcast:15 -> rows 1,3
    y = dpp_u64max_step<0x143, 0xc>(y);  // row_bcast:31 -> rows 2,3
    if ((t & 63) == 63) wbuf[p][t >> 6] = y;
    __syncthreads();
    // ---- block combine: 1 LDS read + 3 DPP row_ror steps (mod-8 rotation) ----
    unsigned long long wm = wbuf[p][t & (NW - 1)];
    wm = dpp_u64max_step<0x121, 0xf>(wm);  // row_ror:1
    wm = dpp_u64max_step<0x122, 0xf>(wm);  // row_ror:2
    wm = dpp_u64max_step<0x124, 0xf>(wm);  // row_ror:4
    worig = (int)(~(unsigned)(wm & 0xffffffffULL));
    p ^= 1;
  }

  __syncthreads();   // swin[] complete before coalesced writeback
  for (int s = t; s < S; s += NT) {
    const int o = swin[s];
    q_out[3*s+0] = sx[o]; q_out[3*s+1] = sy[o]; q_out[3*s+2] = sz[o];
  }
}

// ============================ radius-KNN ============================
#define KNN_CAP 2048

__global__ __launch_bounds__(256) void knn_kernel(const float* __restrict__ cand,
                                                  const float* __restrict__ qpos,
                                                  int nq_per_graph, int n_cand, float r2,
                                                  int* __restrict__ nbr_out,
                                                  int* __restrict__ cnt_out)
{
  const int qi = blockIdx.x;
  const int t = threadIdx.x;
  const int b = qi / nq_per_graph;
  const float* cb = cand + (size_t)b * n_cand * 3;
  const float qx = qpos[3*qi+0], qy = qpos[3*qi+1], qz = qpos[3*qi+2];

  __shared__ unsigned long long keys[KNN_CAP];
  __shared__ int s_cnt;
  if (t == 0) s_cnt = 0;
  __syncthreads();

  for (int i = t; i < n_cand; i += 256) {
    const float dx = __fsub_rn(cb[3*i+0], qx);
    const float dy = __fsub_rn(cb[3*i+1], qy);
    const float dz = __fsub_rn(cb[3*i+2], qz);
    const float d2 = __fadd_rn(__fadd_rn(__fmul_rn(dx, dx), __fmul_rn(dy, dy)),
                               __fmul_rn(dz, dz));
    if (d2 <= r2) {
      const int p = atomicAdd(&s_cnt, 1);
      if (p < KNN_CAP) keys[p] = ((unsigned long long)__float_as_uint(d2) << 32) | (unsigned)i;
    }
  }
  __syncthreads();
  const int M = min(s_cnt, KNN_CAP);
  const int out_n = min(M, 64);
  if (M > 64) {
    int P = 128; while (P < M) P <<= 1;
    for (int i = M + t; i < P; i += 256) keys[i] = ~0ULL;
    __syncthreads();
    for (int k = 2; k <= P; k <<= 1) {
      for (int j = k >> 1; j > 0; j >>= 1) {
        for (int i = t; i < P; i += 256) {
          const int l = i ^ j;
          if (l > i) {
            const unsigned long long a = keys[i], c = keys[l];
            const bool up = ((i & k) == 0);
            if ((a > c) == up) { keys[i] = c; keys[l] = a; }
          }
        }
        __syncthreads();
      }
    }
  }
  if (t < 64) nbr_out[(size_t)qi*64 + t] = (t < out_n) ? (int)(keys[t] & 0xffffffffu) : -1;
  if (t == 0) cnt_out[qi] = out_n;
}

// ============================ SA1 edge MLP (3->64->64->128) + max ============================
__global__ __launch_bounds__(256) void mlp1_kernel(const float* __restrict__ pos,
                                                   const float* __restrict__ q1,
                                                   const int* __restrict__ nbr,
                                                   const int* __restrict__ cnt_,
                                                   const float* __restrict__ W1, const float* __restrict__ b1,
                                                   const float* __restrict__ W2, const float* __restrict__ b2,
                                                   const float* __restrict__ W3, const float* __restrict__ b3,
                                                   float* __restrict__ x1)
{
  const int qi = blockIdx.x;
  const int t = threadIdx.x;
  const int bg = qi >> 12;                       // 4096 queries per graph
  const float* cb = pos + (size_t)bg * 8192 * 3;

  __shared__ float sW1[3*64];
  __shared__ float sb1[64];
  __shared__ float sW2[64*64];
  __shared__ float sb2[64];
  __shared__ float sW3[64*128];
  __shared__ float sb3[128];
  __shared__ float featT[3][64];                 // k-major rel
  __shared__ float h1[64][65];
  __shared__ float h2b[64][65];

  const int cnt = cnt_[qi];
  const float qx = q1[3*qi+0], qy = q1[3*qi+1], qz = q1[3*qi+2];

  if (t < 64) {
    float r0 = 0.f, r1 = 0.f, r2v = 0.f;
    if (t < cnt) {
      const int nb = nbr[(size_t)qi*64 + t];
      r0 = cb[3*nb+0] - qx;
      r1 = cb[3*nb+1] - qy;
      r2v = cb[3*nb+2] - qz;
    }
    featT[0][t] = r0; featT[1][t] = r1; featT[2][t] = r2v;
  }
  for (int i = t; i < 192; i += 256) sW1[i] = W1[i];
  if (t < 64) { sb1[t] = b1[t]; sb2[t] = b2[t]; }
  for (int i = t; i < 4096; i += 256) sW2[i] = W2[i];
  for (int i = t; i < 8192; i += 256) sW3[i] = W3[i];
  if (t < 128) sb3[t] = b3[t];
  __syncthreads();

  const int e = t & 63, cg = t >> 6;
  { // layer1: 16 channels per thread
    const int c0 = cg * 16;
    const float a0 = featT[0][e], a1 = featT[1][e], a2 = featT[2][e];
#pragma unroll
    for (int i = 0; i < 16; ++i) {
      float v = sb1[c0+i];
      v = fmaf(a0, sW1[0*64 + c0+i], v);
      v = fmaf(a1, sW1[1*64 + c0+i], v);
      v = fmaf(a2, sW1[2*64 + c0+i], v);
      h1[e][c0+i] = fmaxf(v, 0.f);
    }
  }
  __syncthreads();
  { // layer2
    const int c0 = cg * 16;
    float acc[16];
#pragma unroll
    for (int i = 0; i < 16; ++i) acc[i] = sb2[c0+i];
    for (int k = 0; k < 64; ++k) {
      const float a = h1[e][k];
      const float4* wp = reinterpret_cast<const float4*>(&sW2[k*64 + c0]);
#pragma unroll
      for (int i = 0; i < 4; ++i) {
        const float4 w = wp[i];
        acc[4*i+0] = fmaf(a, w.x, acc[4*i+0]);
        acc[4*i+1] = fmaf(a, w.y, acc[4*i+1]);
        acc[4*i+2] = fmaf(a, w.z, acc[4*i+2]);
        acc[4*i+3] = fmaf(a, w.w, acc[4*i+3]);
      }
    }
#pragma unroll
    for (int i = 0; i < 16; ++i) h2b[e][c0+i] = fmaxf(acc[i], 0.f);
  }
  __syncthreads();
  float acc3[32];
  const int c0h = cg * 32;
  { // layer3 (no relu)
#pragma unroll
    for (int i = 0; i < 32; ++i) acc3[i] = sb3[c0h+i];
    for (int k = 0; k < 64; ++k) {
      const float a = h2b[e][k];
      const float4* wp = reinterpret_cast<const float4*>(&sW3[k*128 + c0h]);
#pragma unroll
      for (int i = 0; i < 8; ++i) {
        const float4 w = wp[i];
        acc3[4*i+0] = fmaf(a, w.x, acc3[4*i+0]);
        acc3[4*i+1] = fmaf(a, w.y, acc3[4*i+1]);
        acc3[4*i+2] = fmaf(a, w.z, acc3[4*i+2]);
        acc3[4*i+3] = fmaf(a, w.w, acc3[4*i+3]);
      }
    }
  }
  __syncthreads();       // all reads of h1/h2b done before re-staging
  {
    const bool valid = (e < cnt);
#pragma unroll
    for (int i = 0; i < 32; ++i) {
      const float v = valid ? acc3[i] : NEG_INF;
      const int c = c0h + i;
      if (c < 64) h1[e][c] = v; else h2b[e][c-64] = v;
    }
  }
  __syncthreads();
  if (t < 128) {
    float m = NEG_INF;
    if (t < 64) {
      for (int ee = 0; ee < 64; ++ee) m = fmaxf(m, h1[ee][t]);
    } else {
      for (int ee = 0; ee < 64; ++ee) m = fmaxf(m, h2b[ee][t-64]);
    }
    x1[(size_t)qi*128 + t] = m;
  }
}

// ============================ SA2 edge MLP (131->128->128->256) + max ============================
__global__ __launch_bounds__(256) void mlp2_kernel(const float* __restrict__ q1,
                                                   const float* __restrict__ x1,
                                                   const float* __restrict__ q2,
                                                   const int* __restrict__ nbr,
                                                   const int* __restrict__ cnt_,
                                                   const float* __restrict__ W1, const float* __restrict__ b1,
                                                   const float* __restrict__ W2, const float* __restrict__ b2,
                                                   const float* __restrict__ W3, const float* __restrict__ b3,
                                                   float* __restrict__ x2)
{
  const int qi = blockIdx.x;
  const int t = threadIdx.x;
  const int bg = qi >> 10;                       // 1024 queries per graph
  const float* cb = q1 + (size_t)bg * 4096 * 3;
  const float* xb = x1 + (size_t)bg * 4096 * 128;

  __shared__ float sW[131*128];                  // staged layer weights
  __shared__ float sb[256];
  __shared__ float featT[131][64];               // k-major feat; reused as h2
  __shared__ float hbuf[64][129];                // h1; reused as h3 stage
  __shared__ int snb[64];

  const int cnt = cnt_[qi];
  const float qx = q2[3*qi+0], qy = q2[3*qi+1], qz = q2[3*qi+2];

  if (t < 64) {
    const int nb = (t < cnt) ? nbr[(size_t)qi*64 + t] : 0;
    snb[t] = nb;
    float r0 = 0.f, r1 = 0.f, r2v = 0.f;
    if (t < cnt) {
      r0 = cb[3*nb+0] - qx;
      r1 = cb[3*nb+1] - qy;
      r2v = cb[3*nb+2] - qz;
    }
    featT[128][t] = r0; featT[129][t] = r1; featT[130][t] = r2v;
  }
  for (int i = t; i < 131*128; i += 256) sW[i] = W1[i];
  if (t < 128) sb[t] = b1[t];
  __syncthreads();
  for (int idx = t; idx < 64*128; idx += 256) {   // gather x1 features
    const int e = idx >> 7, k = idx & 127;
    featT[k][e] = (e < cnt) ? xb[(size_t)snb[e]*128 + k] : 0.f;
  }
  __syncthreads();

  const int e = t & 63, cg = t >> 6, c0 = cg * 32;
  float acc[32];
  { // layer1: 131 -> 128
#pragma unroll
    for (int i = 0; i < 32; ++i) acc[i] = sb[c0+i];
    for (int k = 0; k < 131; ++k) {
      const float a = featT[k][e];
      const float4* wp = reinterpret_cast<const float4*>(&sW[k*128 + c0]);
#pragma unroll
      for (int i = 0; i < 8; ++i) {
        const float4 w = wp[i];
        acc[4*i+0] = fmaf(a, w.x, acc[4*i+0]);
        acc[4*i+1] = fmaf(a, w.y, acc[4*i+1]);
        acc[4*i+2] = fmaf(a, w.z, acc[4*i+2]);
        acc[4*i+3] = fmaf(a, w.w, acc[4*i+3]);
      }
    }
#pragma unroll
    for (int i = 0; i < 32; ++i) hbuf[e][c0+i] = fmaxf(acc[i], 0.f);
  }
  __syncthreads();
  for (int i = t; i < 128*128; i += 256) sW[i] = W2[i];
  if (t < 128) sb[t] = b2[t];
  __syncthreads();
  { // layer2: 128 -> 128 ; h2 stored k-major into featT region
#pragma unroll
    for (int i = 0; i < 32; ++i) acc[i] = sb[c0+i];
    for (int k = 0; k < 128; ++k) {
      const float a = hbuf[e][k];
      const float4* wp = reinterpret_cast<const float4*>(&sW[k*128 + c0]);
#pragma unroll
      for (int i = 0; i < 8; ++i) {
        const float4 w = wp[i];
        acc[4*i+0] = fmaf(a, w.x, acc[4*i+0]);
        acc[4*i+1] = fmaf(a, w.y, acc[4*i+1]);
        acc[4*i+2] = fmaf(a, w.z, acc[4*i+2]);
        acc[4*i+3] = fmaf(a, w.w, acc[4*i+3]);
      }
    }
  }
  __syncthreads();   // everyone done reading hbuf(h1) and sW(W2)
#pragma unroll
  for (int i = 0; i < 32; ++i) featT[c0+i][e] = fmaxf(acc[i], 0.f);
  __syncthreads();
  // layer3: 128 -> 256, in two column halves (staged W3 halves), masked max
  for (int hh = 0; hh < 2; ++hh) {
    for (int i = t; i < 128*128; i += 256) {
      const int k = i >> 7, c = i & 127;
      sW[i] = W3[k*256 + hh*128 + c];
    }
    if (t < 128) sb[t] = b3[hh*128 + t];
    __syncthreads();
#pragma unroll
    for (int i = 0; i < 32; ++i) acc[i] = sb[c0+i];
    for (int k = 0; k < 128; ++k) {
      const float a = featT[k][e];
      const float4* wp = reinterpret_cast<const float4*>(&sW[k*128 + c0]);
#pragma unroll
      for (int i = 0; i < 8; ++i) {
        const float4 w = wp[i];
        acc[4*i+0] = fmaf(a, w.x, acc[4*i+0]);
        acc[4*i+1] = fmaf(a, w.y, acc[4*i+1]);
        acc[4*i+2] = fmaf(a, w.z, acc[4*i+2]);
        acc[4*i+3] = fmaf(a, w.w, acc[4*i+3]);
      }
    }
    const bool valid = (e < cnt);
#pragma unroll
    for (int i = 0; i < 32; ++i) hbuf[e][c0+i] = valid ? acc[i] : NEG_INF;
    __syncthreads();
    if (t < 128) {
      float m = NEG_INF;
      for (int ee = 0; ee < 64; ++ee) m = fmaxf(m, hbuf[ee][t]);
      x2[(size_t)qi*256 + hh*128 + t] = m;
    }
    __syncthreads();  // hbuf reads + sW reads done before next half
  }
}

// ============================ head MLP (256->256->128->1, sigmoid) ============================
__global__ __launch_bounds__(256) void head_kernel(const float* __restrict__ x2,
                                                   const float* __restrict__ W1, const float* __restrict__ b1,
                                                   const float* __restrict__ W2, const float* __restrict__ b2,
                                                   const float* __restrict__ W3, const float* __restrict__ b3,
                                                   float* __restrict__ out)
{
  const int pt = blockIdx.x;
  const int t = threadIdx.x;
  __shared__ float sx[256];
  __shared__ float sh1[256];
  __shared__ float sh2[128];
  __shared__ float red[128];

  sx[t] = x2[(size_t)pt*256 + t];
  __syncthreads();
  float a1 = b1[t];
  for (int k = 0; k < 256; ++k) a1 = fmaf(sx[k], W1[k*256 + t], a1);
  sh1[t] = fmaxf(a1, 0.f);
  __syncthreads();
  if (t < 128) {
    float a2 = b2[t];
    for (int k = 0; k < 256; ++k) a2 = fmaf(sh1[k], W2[k*128 + t], a2);
    sh2[t] = fmaxf(a2, 0.f);
  }
  __syncthreads();
  if (t < 128) red[t] = sh2[t] * W3[t];
  __syncthreads();
  for (int o = 64; o > 0; o >>= 1) {
    if (t < o) red[t] += red[t + o];
    __syncthreads();
  }
  if (t == 0) {
    const float v = red[0] + b3[0];
    out[pt] = 1.f / (1.f + expf(-v));
  }
}

// ============================ launcher ============================
extern "C" void kernel_launch(void* const* d_in, const int* in_sizes, int n_in,
                              void* d_out, int out_size, void* d_ws, size_t ws_size,
                              hipStream_t stream)
{
  (void)in_sizes; (void)n_in; (void)out_size; (void)ws_size;
  const float* pos  = (const float*)d_in[0];
  // d_in[1] = batch (sorted, equal graphs) — layout implied, unused
  const float* s1W1 = (const float*)d_in[2];  const float* s1b1 = (const float*)d_in[3];
  const float* s1W2 = (const float*)d_in[4];  const float* s1b2 = (const float*)d_in[5];
  const float* s1W3 = (const float*)d_in[6];  const float* s1b3 = (const float*)d_in[7];
  const float* s2W1 = (const float*)d_in[8];  const float* s2b1 = (const float*)d_in[9];
  const float* s2W2 = (const float*)d_in[10]; const float* s2b2 = (const float*)d_in[11];
  const float* s2W3 = (const float*)d_in[12]; const float* s2b3 = (const float*)d_in[13];
  const float* l1W  = (const float*)d_in[14]; const float* l1b  = (const float*)d_in[15];
  const float* l2W  = (const float*)d_in[16]; const float* l2b  = (const float*)d_in[17];
  const float* l3W  = (const float*)d_in[18]; const float* l3b  = (const float*)d_in[19];
  float* out = (float*)d_out;

  char* w = (char*)d_ws;
  size_t off = 0;
  auto alloc = [&](size_t bytes) -> void* {
    void* p = w + off;
    off += (bytes + 255) & ~(size_t)255;
    return p;
  };
  float* q1   = (float*)alloc((size_t)2*4096*3*4);
  float* q2   = (float*)alloc((size_t)2*1024*3*4);
  float* x1   = (float*)alloc((size_t)8192*128*4);
  float* x2   = (float*)alloc((size_t)2048*256*4);
  int*   nbr1 = (int*)alloc((size_t)8192*64*4);
  int*   cnt1 = (int*)alloc((size_t)8192*4);
  int*   nbr2 = (int*)alloc((size_t)2048*64*4);
  int*   cnt2 = (int*)alloc((size_t)2048*4);

  const float R1SQ = (float)(0.2 * 0.2);   // mirrors Python double math -> f32
  const float R2SQ = (float)(0.4 * 0.4);

  fpsp_kernel<8192, 16, 4096><<<dim3(2), dim3(512), 0, stream>>>(pos, q1);
  knn_kernel<<<dim3(8192), dim3(256), 0, stream>>>(pos, q1, 4096, 8192, R1SQ, nbr1, cnt1);
  mlp1_kernel<<<dim3(8192), dim3(256), 0, stream>>>(pos, q1, nbr1, cnt1,
                                                    s1W1, s1b1, s1W2, s1b2, s1W3, s1b3, x1);
  fpsp_kernel<4096, 8, 1024><<<dim3(2), dim3(512), 0, stream>>>(q1, q2);
  knn_kernel<<<dim3(2048), dim3(256), 0, stream>>>(q1, q2, 1024, 4096, R2SQ, nbr2, cnt2);
  mlp2_kernel<<<dim3(2048), dim3(256), 0, stream>>>(q1, x1, q2, nbr2, cnt2,
                                                    s2W1, s2b1, s2W2, s2b2, s2W3, s2b3, x2);
  head_kernel<<<dim3(2048), dim3(256), 0, stream>>>(x2, l1W, l1b, l2W, l2b, l3W, l3b, out);
}